// Round 7
// baseline (96.612 us; speedup 1.0000x reference)
//
#include <hip/hip_runtime.h>
#include <math.h>

#define KC 3
#define S 12
#define SS 1728
#define AB 32
#define TLEN 64
#define NTHREADS 448
#define NWAVES 7
#define NSLICE 432
#define LN2F 0.69314718055994530942f

__global__ __launch_bounds__(NTHREADS, 2)
void hmm_fwd_kernel(const int* __restrict__ ys,
                    const float* __restrict__ transition,  // [3][12][12]
                    const float* __restrict__ emission,    // [3][12][32]
                    const float* __restrict__ choice,      // [3]
                    const float* __restrict__ prior,       // [3][12]
                    float* __restrict__ out)
{
    // Ping-pong planes, each in its OWNER chain's ordering, rows of 12 (48B):
    //   P0[12*(12*s1+s2) + s0], P1[12*(12*s0+s2) + s1], P2[12*(12*s0+s1) + s2]
    __shared__ __align__(16) float PL[2][KC][SS];
    __shared__ __align__(16) float T_s[KC][S][S];
    __shared__ __align__(16) float ECt[KC][AB][S];  // [k][y][j]
    __shared__ float p_lin[KC][S];
    __shared__ float c_lin[KC];
    __shared__ int   ys_s[TLEN];
    __shared__ float wsum[NWAVES];

    const int tid = threadIdx.x;

    // ---------------- setup: linear-space tables ----------------
    if (tid < TLEN) ys_s[tid] = ys[tid];

    if (tid == 0) {
        float m = fmaxf(fmaxf(choice[0], choice[1]), choice[2]);
        float e0 = __expf(choice[0]-m), e1 = __expf(choice[1]-m), e2 = __expf(choice[2]-m);
        float inv = 1.f / (e0+e1+e2);
        c_lin[0] = e0*inv; c_lin[1] = e1*inv; c_lin[2] = e2*inv;
    }
    if (tid >= 1 && tid < 1 + KC) {
        int k = tid - 1;
        float m = -INFINITY;
        #pragma unroll
        for (int i = 0; i < S; ++i) m = fmaxf(m, prior[k*S + i]);
        float ev[S]; float s = 0.f;
        #pragma unroll
        for (int i = 0; i < S; ++i) { ev[i] = __expf(prior[k*S + i] - m); s += ev[i]; }
        float inv = 1.f / s;
        #pragma unroll
        for (int i = 0; i < S; ++i) p_lin[k][i] = ev[i] * inv;
    }
    if (tid >= 64 && tid < 64 + KC*S) {
        int r = tid - 64;
        int k = r / S, i = r % S;
        const float* row = transition + (k*S + i)*S;
        float m = -INFINITY;
        #pragma unroll
        for (int j = 0; j < S; ++j) m = fmaxf(m, row[j]);
        float ev[S]; float s = 0.f;
        #pragma unroll
        for (int j = 0; j < S; ++j) { ev[j] = __expf(row[j] - m); s += ev[j]; }
        float inv = 1.f / s;
        #pragma unroll
        for (int j = 0; j < S; ++j) T_s[k][i][j] = ev[j] * inv;
    }
    if (tid >= 128 && tid < 128 + KC*S) {    // emission -> ECt[k][y][j] = C[k]*softmax
        int r = tid - 128;
        int k = r / S, sj = r % S;
        float cm = fmaxf(fmaxf(choice[0], choice[1]), choice[2]);
        float ce = __expf(choice[k]-cm) /
                   (__expf(choice[0]-cm) + __expf(choice[1]-cm) + __expf(choice[2]-cm));
        const float* row = emission + (k*S + sj)*AB;
        float m = -INFINITY;
        #pragma unroll
        for (int a = 0; a < AB; ++a) m = fmaxf(m, row[a]);
        float ev[AB]; float s = 0.f;
        #pragma unroll
        for (int a = 0; a < AB; ++a) { ev[a] = __expf(row[a] - m); s += ev[a]; }
        float inv = ce / s;
        #pragma unroll
        for (int a = 0; a < AB; ++a) ECt[k][a][sj] = ev[a] * inv;
    }
    __syncthreads();

    // ---------------- per-thread statics ----------------
    const bool active = tid < NSLICE;
    const int ct = active ? tid : (NSLICE - 1);   // clamped for safe pointer math
    const int sk = ct / 144;                      // chain
    const int q  = ct % 144;
    const int qh = q / 12, ql = q % 12;

    // foreign base word-offsets (j=0 position in each foreign plane)
    int offA, offB;                               // A: first foreign, B: second
    if (sk == 0)      { offA = 12*ql + qh;        offB = 12*qh + ql;        } // P1(s144), P2(s144)
    else if (sk == 1) { offA = 12*ql + qh;        offB = 144*qh + ql;       } // P0(s144), P2(s12)
    else              { offA = 144*ql + qh;       offB = 144*qh + ql;       } // P0(s12),  P1(s12)

    const int fApl = (sk == 0) ? 1 : 0;           // plane index of foreign A
    const int fBpl = (sk == 2) ? 1 : 2;           // plane index of foreign B

    const float* Tp  = &T_s[sk][0][0];
    const float* ecp = &ECt[sk][0][0];

    // pointer pairs for ping-pong (static, swap-free: two inlined half-steps)
    const float* fA0 = &PL[0][fApl][offA];
    const float* fB0 = &PL[0][fBpl][offB];
    float*       wp0 = &PL[0][sk][12*q];
    const float* fA1 = &PL[1][fApl][offA];
    const float* fB1 = &PL[1][fBpl][offB];
    float*       wp1 = &PL[1][sk][12*q];

    // init plane values + own cache
    float own[S];
    if (active) {
        float pq = (sk == 0) ? p_lin[1][qh] * p_lin[2][ql]
                 : (sk == 1) ? p_lin[0][qh] * p_lin[2][ql]
                 :             p_lin[0][qh] * p_lin[1][ql];
        float ck = c_lin[sk];
        #pragma unroll
        for (int j = 0; j < S; ++j) {
            own[j] = p_lin[sk][j] * pq * ck;
            wp0[j] = own[j];
        }
    }
    __syncthreads();

    float logR = 0.f, invR = 1.f;

    auto do_step = [&](int t, const float* fA, const float* fB, float* wp) {
        const int y = ys_s[t];
        if (active) {
            const float* eb = ecp + y*S;
            float4 e0 = *reinterpret_cast<const float4*>(&eb[0]);
            float4 e1 = *reinterpret_cast<const float4*>(&eb[4]);
            float4 e2 = *reinterpret_cast<const float4*>(&eb[8]);

            // foreign gathers: literal strides -> ds_read2_b32 merging
            float fa[S], fb[S];
            if (sk == 0) {
                #pragma unroll
                for (int i = 0; i < S; ++i) { fa[i] = fA[144*i]; fb[i] = fB[144*i]; }
            } else if (sk == 1) {
                #pragma unroll
                for (int i = 0; i < S; ++i) { fa[i] = fA[144*i]; fb[i] = fB[12*i]; }
            } else {
                #pragma unroll
                for (int i = 0; i < S; ++i) { fa[i] = fA[12*i];  fb[i] = fB[12*i]; }
            }

            float bv[S];
            #pragma unroll
            for (int i = 0; i < S; ++i) bv[i] = (own[i] + fa[i] + fb[i]) * invR;

            float acc[S];
            #pragma unroll
            for (int j = 0; j < S; ++j) acc[j] = 0.f;
            #pragma unroll
            for (int i = 0; i < S; ++i) {
                // T row broadcast (same address across the chain subgroup)
                float4 t0 = *reinterpret_cast<const float4*>(&Tp[12*i + 0]);
                float4 t1 = *reinterpret_cast<const float4*>(&Tp[12*i + 4]);
                float4 t2 = *reinterpret_cast<const float4*>(&Tp[12*i + 8]);
                const float bb = bv[i];
                acc[0] = __builtin_fmaf(bb, t0.x, acc[0]);
                acc[1] = __builtin_fmaf(bb, t0.y, acc[1]);
                acc[2] = __builtin_fmaf(bb, t0.z, acc[2]);
                acc[3] = __builtin_fmaf(bb, t0.w, acc[3]);
                acc[4] = __builtin_fmaf(bb, t1.x, acc[4]);
                acc[5] = __builtin_fmaf(bb, t1.y, acc[5]);
                acc[6] = __builtin_fmaf(bb, t1.z, acc[6]);
                acc[7] = __builtin_fmaf(bb, t1.w, acc[7]);
                acc[8] = __builtin_fmaf(bb, t2.x, acc[8]);
                acc[9] = __builtin_fmaf(bb, t2.y, acc[9]);
                acc[10] = __builtin_fmaf(bb, t2.z, acc[10]);
                acc[11] = __builtin_fmaf(bb, t2.w, acc[11]);
            }

            own[0]=acc[0]*e0.x; own[1]=acc[1]*e0.y; own[2] =acc[2]*e0.z;  own[3] =acc[3]*e0.w;
            own[4]=acc[4]*e1.x; own[5]=acc[5]*e1.y; own[6] =acc[6]*e1.z;  own[7] =acc[7]*e1.w;
            own[8]=acc[8]*e2.x; own[9]=acc[9]*e2.y; own[10]=acc[10]*e2.z; own[11]=acc[11]*e2.w;

            float4* pw = reinterpret_cast<float4*>(wp);
            pw[0] = make_float4(own[0], own[1], own[2],  own[3]);
            pw[1] = make_float4(own[4], own[5], own[6],  own[7]);
            pw[2] = make_float4(own[8], own[9], own[10], own[11]);
        }

        if ((t & 7) == 7) {
            float part = 0.f;
            if (active) {
                #pragma unroll
                for (int j = 0; j < S; ++j) part += own[j];
            }
            #pragma unroll
            for (int w = 32; w > 0; w >>= 1) part += __shfl_xor(part, w);
            if ((tid & 63) == 0) wsum[tid >> 6] = part;
        }
        __syncthreads();   // writes to next plane + wsum visible

        if ((t & 7) == 7 && t < TLEN-1) {
            float R = wsum[0];
            #pragma unroll
            for (int w = 1; w < NWAVES; ++w) R += wsum[w];
            invR = __builtin_amdgcn_rcpf(R);
            logR += __log2f(R);
        } else {
            invR = 1.f;
        }
    };

    for (int tt = 0; tt < TLEN; tt += 2) {
        do_step(tt,     fA0, fB0, wp1);   // read planes[0], write planes[1]
        do_step(tt + 1, fA1, fB1, wp0);   // read planes[1], write planes[0]
    }

    // final: total mass at t=63 is in wsum (its normalizer never applied)
    if (tid == 0) {
        float R = wsum[0];
        #pragma unroll
        for (int w = 1; w < NWAVES; ++w) R += wsum[w];
        out[0] = LN2F * (__log2f(R) + logR);
    }
}

extern "C" void kernel_launch(void* const* d_in, const int* in_sizes, int n_in,
                              void* d_out, int out_size, void* d_ws, size_t ws_size,
                              hipStream_t stream) {
    const int*   ys         = (const int*)  d_in[0];
    const float* transition = (const float*)d_in[1];
    const float* emission   = (const float*)d_in[2];
    const float* choice     = (const float*)d_in[3];
    const float* prior      = (const float*)d_in[4];
    float* out = (float*)d_out;

    hipLaunchKernelGGL(hmm_fwd_kernel, dim3(1), dim3(NTHREADS), 0, stream,
                       ys, transition, emission, choice, prior, out);
}